// Round 7
// baseline (165.476 us; speedup 1.0000x reference)
//
#include <hip/hip_runtime.h>
#include <hip/hip_bf16.h>

#define BB 64
#define CC 64
#define TT_ 128
#define VV 25
#define RR 8
#define TS_ 9
#define OO 64
#define VCH 5
#define XBF_STRIDE 5632   // u16 per (b,c) block: 11264 B = 11 x 1024-B DMA chunks

typedef __hip_bfloat16 bf16;
typedef __attribute__((ext_vector_type(8))) short short8;
typedef __attribute__((ext_vector_type(4))) short s16x4;
typedef __attribute__((ext_vector_type(4))) float f32x4;

__device__ __forceinline__ unsigned short f2b(float f) {
    bf16 h = __float2bfloat16(f);
    return __builtin_bit_cast(unsigned short, h);
}

// scatter one float4 (flat idx i4*4 in [t][v] order) into padded bf16 image
__device__ __forceinline__ void putf4(unsigned short* xp, int i4, float4 f) {
    int idx = i4 * 4;
    int t = idx / VV, v = idx - t * VV;
    float fe[4] = {f.x, f.y, f.z, f.w};
    #pragma unroll
    for (int e = 0; e < 4; e++) {
        xp[(t + 8) * 40 + v] = f2b(fe[e]);
        if (++v == VV) { v = 0; t++; }
    }
}

// ---------------------------------------------------------------------------
// Kernel 1: xm[b,c,v] = mean over t of x[b,c,t,v]  AND  xbf[b,c] = padded
//   bf16 image [141][40] (rows 0..7 causal-pad zeros, cols 25..31 v-pad zeros,
//   rows 8..135 = x[t][v]). k_z later DMA-copies this image straight to LDS.
// ---------------------------------------------------------------------------
__global__ __launch_bounds__(256) void k_mean(const float* __restrict__ x,
                                              float* __restrict__ xm,
                                              unsigned short* __restrict__ xbf) {
    __shared__ float smf[800];
    __shared__ __align__(16) unsigned short xp[141 * 40];   // 11280 B
    int bc = blockIdx.x;
    int tid = threadIdx.x;
    const float4* p4 = (const float4*)(x + (size_t)bc * TT_ * VV);
    float4 a, b, c, d;
    if (tid < 200) {           // issue loads first; they overlap the zero-fill
        a = p4[tid];
        b = p4[tid + 200];
        c = p4[tid + 400];
        d = p4[tid + 600];
    }
    // zero the whole padded image (2820 u32 = 11280 B)
    for (int i = tid; i < 2820; i += 256) ((unsigned int*)xp)[i] = 0u;
    __syncthreads();
    if (tid < 200) {
        float4 s;
        s.x = a.x + b.x + c.x + d.x;
        s.y = a.y + b.y + c.y + d.y;
        s.z = a.z + b.z + c.z + d.z;
        s.w = a.w + b.w + c.w + d.w;
        ((float4*)smf)[tid] = s;
        putf4(xp, tid,       a);
        putf4(xp, tid + 200, b);
        putf4(xp, tid + 400, c);
        putf4(xp, tid + 600, d);
    }
    __syncthreads();
    if (tid < VV) {
        float tot = 0.f;
        #pragma unroll
        for (int m = 0; m < 32; m++) tot += smf[tid + VV * m];  // idx%25 == tid
        xm[bc * VV + tid] = tot * (1.0f / TT_);
    }
    // copy padded image to global, coalesced (704 uint4 = 11264 B)
    uint4* dst = (uint4*)(xbf + (size_t)bc * XBF_STRIDE);
    const uint4* src = (const uint4*)xp;
    for (int i = tid; i < 704; i += 256) dst[i] = src[i];
}

// ---------------------------------------------------------------------------
// Kernel 2: rel[b][v][i][r] = tanh(x1[b,r,v] - x2[b,r,i])   (fp32)
//   Grid (b, v-chunk of 5) = 320 blocks. tanh via (e-1)/(e+1), e=__expf(2d).
// ---------------------------------------------------------------------------
__global__ __launch_bounds__(256) void k_rel(const float* __restrict__ xm,
                                             const float* __restrict__ W1,
                                             const float* __restrict__ b1,
                                             const float* __restrict__ W2,
                                             const float* __restrict__ b2,
                                             float* __restrict__ rel) {
    __shared__ float xms[CC * VV];
    __shared__ float x1s[RR][VCH];
    __shared__ float x2s[RR][VV];
    int b = blockIdx.x / 5, g = blockIdx.x % 5;
    int v0 = g * VCH;
    int tid = threadIdx.x;
    for (int i = tid; i < CC * VV; i += 256) xms[i] = xm[b * CC * VV + i];
    __syncthreads();
    // 240 projection tasks: 40 = x1 (r, v-local), 200 = x2 (r, i)
    if (tid < 240) {
        if (tid < 40) {
            int r = tid / VCH, vl = tid % VCH;
            float s1 = b1[r];
            for (int c = 0; c < CC; c++) s1 += W1[r * CC + c] * xms[c * VV + v0 + vl];
            x1s[r][vl] = s1;
        } else {
            int t = tid - 40;
            int r = t / VV, i = t % VV;
            float s2 = b2[r];
            for (int c = 0; c < CC; c++) s2 += W2[r * CC + c] * xms[c * VV + i];
            x2s[r][i] = s2;
        }
    }
    __syncthreads();
    // 1000 outputs, contiguous [v0*200, v0*200+1000) in rel[b]
    float* relb = rel + (size_t)b * VV * VV * RR + (size_t)v0 * VV * RR;
    for (int idx = tid; idx < VCH * VV * RR; idx += 256) {
        int r = idx % RR;
        int i = (idx / RR) % VV;
        int vl = idx / (RR * VV);
        float d = x1s[r][vl] - x2s[r][i];
        float e = __expf(2.0f * d);
        relb[idx] = (e - 1.0f) / (e + 1.0f);
    }
}

// ---------------------------------------------------------------------------
// Kernel 3 (MFMA): z[b,c,t,i] = sum_{v,s} x[b,c,t+s-8,v] * Ad[s,v,i] -> bf16
//   x staging = 11 global_load_lds dwordx4 chunk-DMAs from the prebuilt xbf
//   image (no VGPR round-trip, no cvt, no pad-zeroing). Ad compute + MFMA
//   unchanged. __syncthreads drains vmcnt -> DMA completion is implicit.
// ---------------------------------------------------------------------------
__global__ __launch_bounds__(512) void k_z(const unsigned short* __restrict__ xbf,
                                           const float* __restrict__ Ag,
                                           const float* __restrict__ W4,
                                           const float* __restrict__ b4,
                                           const float* __restrict__ rel,
                                           bf16* __restrict__ zws) {
    __shared__ __align__(16) unsigned short xpadB[141 * 40];     // 11280 B
    __shared__ __align__(16) unsigned short AdbS[TS_ * 32 * 40]; // 23040 B

    int tid = threadIdx.x;
    int bc = blockIdx.x;
    int b = bc / CC, c = bc % CC;
    int lane = tid & 63, w = tid >> 6;

    // DMA the padded x image: 11 chunks x 1024 B (wave-uniform LDS base)
    {
        const char* gx = (const char*)(xbf + (size_t)bc * XBF_STRIDE);
        char* lx = (char*)xpadB;
        __builtin_amdgcn_global_load_lds(
            (const __attribute__((address_space(1))) void*)(gx + w * 1024 + lane * 16),
            (__attribute__((address_space(3))) void*)(lx + w * 1024), 16, 0, 0);
        if (w < 3)
            __builtin_amdgcn_global_load_lds(
                (const __attribute__((address_space(1))) void*)(gx + (8 + w) * 1024 + lane * 16),
                (__attribute__((address_space(3))) void*)(lx + (8 + w) * 1024), 16, 0, 0);
    }
    // AdbS v-pad: all 288 rows, cols 25..31 = 0 (row per thread, no div)
    if (tid >= 224) {
        int base = (tid - 224) * 40 + 25;
        #pragma unroll
        for (int k = 0; k < 7; k++) AdbS[base + k] = 0;
    }

    // Ad compute (fp32) -> AdbS bf16; W4/b4 block-uniform scalar loads
    const float* relb = rel + (size_t)b * VV * VV * RR;
    const float* W4c = W4 + c * TS_ * RR;
    const float* b4c = b4 + c * TS_;
    for (int task = tid; task < VV * VV; task += 512) {
        int v = task / VV, i = task % VV;
        const float4* r4 = (const float4*)(relb + (size_t)task * RR);
        float4 ra = r4[0], rb_ = r4[1];
        float av = Ag[task];
        #pragma unroll
        for (int s = 0; s < TS_; s++) {
            float a2 = b4c[s] + av;
            a2 += W4c[s*8+0] * ra.x  + W4c[s*8+1] * ra.y
                + W4c[s*8+2] * ra.z  + W4c[s*8+3] * ra.w;
            a2 += W4c[s*8+4] * rb_.x + W4c[s*8+5] * rb_.y
                + W4c[s*8+6] * rb_.z + W4c[s*8+7] * rb_.w;
            AdbS[(s * 32 + i) * 40 + v] = f2b(a2);
        }
    }
    __syncthreads();   // drains vmcnt: DMA chunks + lgkm all complete

    // MFMA: wave w -> m-tile w, n-tiles {0,1}, 9 taps (18 mfma/wave)
    int ml = lane & 15, qd = lane >> 4;
    f32x4 acc00 = {0.f, 0.f, 0.f, 0.f};
    f32x4 acc01 = acc00;
    int rowA0 = w * 16 + ml;
    #pragma unroll
    for (int s = 0; s < TS_; s++) {
        short8 a0 = *(const short8*)&xpadB[(rowA0 + s) * 40 + qd * 8];
        short8 b0 = *(const short8*)&AdbS[(s * 32 + ml) * 40 + qd * 8];
        short8 b1 = *(const short8*)&AdbS[(s * 32 + 16 + ml) * 40 + qd * 8];
        acc00 = __builtin_amdgcn_mfma_f32_16x16x32_bf16(a0, b0, acc00, 0, 0, 0);
        acc01 = __builtin_amdgcn_mfma_f32_16x16x32_bf16(a0, b1, acc01, 0, 0, 0);
    }

    bf16* zb = zws + (size_t)bc * TT_ * VV;
    int t0 = w * 16 + qd * 4;
    int i0 = ml, i1 = 16 + ml;
    #pragma unroll
    for (int r = 0; r < 4; r++)
        zb[(t0 + r) * VV + i0] = __float2bfloat16(acc00[r]);
    if (i1 < VV) {
        #pragma unroll
        for (int r = 0; r < 4; r++)
            zb[(t0 + r) * VV + i1] = __float2bfloat16(acc01[r]);
    }
}

// ---------------------------------------------------------------------------
// Kernel 4 (MFMA): out[b,o,tj] = sum_c W3[o,c]*z[b,c,tj] + b3[o]  -> fp32
// ---------------------------------------------------------------------------
__global__ __launch_bounds__(256) void k_conv3(const bf16* __restrict__ zws,
                                               const float* __restrict__ W3,
                                               const float* __restrict__ b3,
                                               float* __restrict__ out) {
    __shared__ __align__(16) unsigned short w3b[OO * 72];   // 9216 B
    __shared__ __align__(16) unsigned short zl[CC * 130];   // 16640 B
    __shared__ float b3l[OO];
    int tid = threadIdx.x;
    int b = blockIdx.x / 25, tile = blockIdx.x % 25;
    int tj0 = tile * 128;

    if (tid < OO) b3l[tid] = b3[tid];
    // W3 [o][c] fp32 -> bf16 LDS (A operand, k-contiguous), 4-wide packed
    const float4* W3v = (const float4*)W3;
    for (int idx = tid; idx < OO * CC / 4; idx += 256) {
        float4 f = W3v[idx];
        int o = idx >> 4, c4 = (idx & 15) * 4;
        s16x4 s4;
        s4[0] = (short)f2b(f.x);
        s4[1] = (short)f2b(f.y);
        s4[2] = (short)f2b(f.z);
        s4[3] = (short)f2b(f.w);
        *(s16x4*)&w3b[o * 72 + c4] = s4;
    }
    // z tile: natural [c][j] layout, packed uint copies (coalesced, conflict-free)
    const unsigned int* zg = (const unsigned int*)(zws + (size_t)b * CC * (TT_ * VV));
    for (int idu = tid; idu < CC * 64; idu += 256) {
        int c = idu >> 6, ju = idu & 63;
        ((unsigned int*)zl)[c * 65 + ju] = zg[c * 1600 + (tj0 >> 1) + ju];
    }
    __syncthreads();

    int lane = tid & 63, wv = tid >> 6;
    int ml = lane & 15, qd = lane >> 4;
    f32x4 acc[4][2];
    #pragma unroll
    for (int m = 0; m < 4; m++)
        #pragma unroll
        for (int nl = 0; nl < 2; nl++) acc[m][nl] = (f32x4){0.f, 0.f, 0.f, 0.f};

    #pragma unroll
    for (int k0 = 0; k0 < 2; k0++) {
        short8 a[4];
        #pragma unroll
        for (int m = 0; m < 4; m++)
            a[m] = *(const short8*)&w3b[(m * 16 + ml) * 72 + k0 * 32 + qd * 8];
        #pragma unroll
        for (int nl = 0; nl < 2; nl++) {
            int col = (2 * wv + nl) * 16 + ml;
            int cb = k0 * 32 + qd * 8;
            short8 bf;
            #pragma unroll
            for (int j = 0; j < 8; j++)
                bf[j] = (short)zl[(cb + j) * 130 + col];
            #pragma unroll
            for (int m = 0; m < 4; m++)
                acc[m][nl] = __builtin_amdgcn_mfma_f32_16x16x32_bf16(a[m], bf, acc[m][nl], 0, 0, 0);
        }
    }

    float* ob = out + (size_t)b * OO * (TT_ * VV) + tj0;
    #pragma unroll
    for (int m = 0; m < 4; m++)
        #pragma unroll
        for (int nl = 0; nl < 2; nl++) {
            int col = (2 * wv + nl) * 16 + ml;
            #pragma unroll
            for (int r = 0; r < 4; r++) {
                int o = m * 16 + qd * 4 + r;
                ob[(size_t)o * (TT_ * VV) + col] = acc[m][nl][r] + b3l[o];
            }
        }
}

// ---------------------------------------------------------------------------
extern "C" void kernel_launch(void* const* d_in, const int* in_sizes, int n_in,
                              void* d_out, int out_size, void* d_ws, size_t ws_size,
                              hipStream_t stream) {
    const float* x  = (const float*)d_in[0];
    const float* A  = (const float*)d_in[1];
    const float* W1 = (const float*)d_in[2];
    const float* b1 = (const float*)d_in[3];
    const float* W2 = (const float*)d_in[4];
    const float* b2 = (const float*)d_in[5];
    const float* W4 = (const float*)d_in[6];
    const float* b4 = (const float*)d_in[7];
    const float* W3 = (const float*)d_in[8];
    const float* b3 = (const float*)d_in[9];
    float* out = (float*)d_out;

    char* ws = (char*)d_ws;
    float* xm = (float*)(ws);                            // 409,600 B
    float* rel = (float*)(ws + 409600);                  // 1,280,000 B
    bf16*  zws = (bf16*)(ws + 1689600);                  // 26,214,400 B
    unsigned short* xbf = (unsigned short*)(ws + 27904000); // 46,137,344 B

    k_mean <<<BB * CC, 256, 0, stream>>>(x, xm, xbf);
    k_rel  <<<BB * 5,  256, 0, stream>>>(xm, W1, b1, W2, b2, rel);
    k_z    <<<BB * CC, 512, 0, stream>>>(xbf, A, W4, b4, rel, zws);
    k_conv3<<<BB * 25, 256, 0, stream>>>(zws, W3, b3, out);
}

// Round 8
// 160.220 us; speedup vs baseline: 1.0328x; 1.0328x over previous
//
#include <hip/hip_runtime.h>
#include <hip/hip_bf16.h>

#define BB 64
#define CC 64
#define TT_ 128
#define VV 25
#define RR 8
#define TS_ 9
#define OO 64
#define VCH 5

typedef __hip_bfloat16 bf16;
typedef __attribute__((ext_vector_type(8))) short short8;
typedef __attribute__((ext_vector_type(4))) short s16x4;
typedef __attribute__((ext_vector_type(4))) float f32x4;

__device__ __forceinline__ unsigned short f2b(float f) {
    bf16 h = __float2bfloat16(f);
    return __builtin_bit_cast(unsigned short, h);
}

// ---------------------------------------------------------------------------
// Kernel 1: xm[b,c,v] = mean over t of x[b,c,t,v]. Block per (b,c).
//   float4 loads (800 f4 per block); phase trick: f4 index j and j+200 have
//   flat offsets differing by 800 == 0 (mod 25), so component e of
//   {j, j+200, j+400, j+600} all share v-phase (4j+e) % 25.
// ---------------------------------------------------------------------------
__global__ __launch_bounds__(256) void k_mean(const float* __restrict__ x,
                                              float* __restrict__ xm) {
    __shared__ float smf[800];
    int bc = blockIdx.x;
    int tid = threadIdx.x;
    const float4* p4 = (const float4*)(x + (size_t)bc * TT_ * VV);
    if (tid < 200) {
        float4 a = p4[tid];
        float4 b = p4[tid + 200];
        float4 c = p4[tid + 400];
        float4 d = p4[tid + 600];
        float4 s;
        s.x = a.x + b.x + c.x + d.x;
        s.y = a.y + b.y + c.y + d.y;
        s.z = a.z + b.z + c.z + d.z;
        s.w = a.w + b.w + c.w + d.w;
        ((float4*)smf)[tid] = s;
    }
    __syncthreads();
    if (tid < VV) {
        float tot = 0.f;
        #pragma unroll
        for (int m = 0; m < 32; m++) tot += smf[tid + VV * m];  // idx%25 == tid
        xm[bc * VV + tid] = tot * (1.0f / TT_);
    }
}

// ---------------------------------------------------------------------------
// Kernel 2: rel[b][v][i][r] = tanh(x1[b,r,v] - x2[b,r,i])   (fp32)
//   Grid (b, v-chunk of 5) = 320 blocks. tanh via (e-1)/(e+1), e=__expf(2d).
// ---------------------------------------------------------------------------
__global__ __launch_bounds__(256) void k_rel(const float* __restrict__ xm,
                                             const float* __restrict__ W1,
                                             const float* __restrict__ b1,
                                             const float* __restrict__ W2,
                                             const float* __restrict__ b2,
                                             float* __restrict__ rel) {
    __shared__ float xms[CC * VV];
    __shared__ float x1s[RR][VCH];
    __shared__ float x2s[RR][VV];
    int b = blockIdx.x / 5, g = blockIdx.x % 5;
    int v0 = g * VCH;
    int tid = threadIdx.x;
    for (int i = tid; i < CC * VV; i += 256) xms[i] = xm[b * CC * VV + i];
    __syncthreads();
    // 240 projection tasks: 40 = x1 (r, v-local), 200 = x2 (r, i)
    if (tid < 240) {
        if (tid < 40) {
            int r = tid / VCH, vl = tid % VCH;
            float s1 = b1[r];
            for (int c = 0; c < CC; c++) s1 += W1[r * CC + c] * xms[c * VV + v0 + vl];
            x1s[r][vl] = s1;
        } else {
            int t = tid - 40;
            int r = t / VV, i = t % VV;
            float s2 = b2[r];
            for (int c = 0; c < CC; c++) s2 += W2[r * CC + c] * xms[c * VV + i];
            x2s[r][i] = s2;
        }
    }
    __syncthreads();
    // 1000 outputs, contiguous [v0*200, v0*200+1000) in rel[b]
    float* relb = rel + (size_t)b * VV * VV * RR + (size_t)v0 * VV * RR;
    for (int idx = tid; idx < VCH * VV * RR; idx += 256) {
        int r = idx % RR;
        int i = (idx / RR) % VV;
        int vl = idx / (RR * VV);
        float d = x1s[r][vl] - x2s[r][i];
        float e = __expf(2.0f * d);
        relb[idx] = (e - 1.0f) / (e + 1.0f);
    }
}

// ---------------------------------------------------------------------------
// Kernel 3 (MFMA): z[b,c,t,i] = sum_{v,s} x[b,c,t+s-8,v] * Ad[s,v,i] -> bf16
//   R3 structure (best measured): 256 threads, single barrier, wave wv ->
//   m-tiles {2wv,2wv+1} x n-tiles {0,1}. Pad fills use direct row-per-thread
//   maps (no div/mod chains) — arithmetic-identical to R3.
// ---------------------------------------------------------------------------
__global__ __launch_bounds__(256) void k_z(const float* __restrict__ x,
                                           const float* __restrict__ Ag,
                                           const float* __restrict__ W4,
                                           const float* __restrict__ b4,
                                           const float* __restrict__ rel,
                                           bf16* __restrict__ zws) {
    __shared__ __align__(16) unsigned short xpadB[136 * 40];     // 10880 B
    __shared__ __align__(16) unsigned short AdbS[TS_ * 32 * 40]; // 23040 B

    int tid = threadIdx.x;
    int bc = blockIdx.x;
    int b = bc / CC, c = bc % CC;

    // causal pad: rows 0..7, cols 0..31 = 0 (u32 writes; cols 32..39 never read)
    if (tid < 128) ((unsigned int*)xpadB)[(tid >> 4) * 20 + (tid & 15)] = 0u;
    // xpadB v-pad: rows 8..135, cols 25..31 = 0 (row per thread, no div)
    if (tid >= 128) {
        int base = (8 + (tid - 128)) * 40 + 25;
        #pragma unroll
        for (int k = 0; k < 7; k++) xpadB[base + k] = 0;
    }
    // AdbS v-pad: all 288 rows, cols 25..31 = 0 (rows i>=25 feed discarded
    // lanes only; row per thread + 32-thread second pass, no div)
    {
        int base = tid * 40 + 25;
        #pragma unroll
        for (int k = 0; k < 7; k++) AdbS[base + k] = 0;
        if (tid < 32) {
            int base2 = (256 + tid) * 40 + 25;
            #pragma unroll
            for (int k = 0; k < 7; k++) AdbS[base2 + k] = 0;
        }
    }
    // stage x (fp32 -> bf16), t' = t + 8; incremental t/v (one div per float4)
    const float4* xg4 = (const float4*)(x + (size_t)bc * TT_ * VV);
    for (int i4 = tid; i4 < TT_ * VV / 4; i4 += 256) {
        float4 f = xg4[i4];
        int idx = i4 * 4;
        int t = idx / VV, v = idx - t * VV;
        float fe[4] = {f.x, f.y, f.z, f.w};
        #pragma unroll
        for (int e = 0; e < 4; e++) {
            xpadB[(t + 8) * 40 + v] = f2b(fe[e]);
            v++;
            if (v == VV) { v = 0; t++; }
        }
    }

    // Ad compute (fp32) -> AdbS bf16; W4/b4 block-uniform scalar loads
    const float* relb = rel + (size_t)b * VV * VV * RR;
    const float* W4c = W4 + c * TS_ * RR;
    const float* b4c = b4 + c * TS_;
    for (int task = tid; task < VV * VV; task += 256) {
        int v = task / VV, i = task % VV;
        const float4* r4 = (const float4*)(relb + (size_t)task * RR);
        float4 ra = r4[0], rb_ = r4[1];
        float av = Ag[task];
        #pragma unroll
        for (int s = 0; s < TS_; s++) {
            float a2 = b4c[s] + av;
            a2 += W4c[s*8+0] * ra.x  + W4c[s*8+1] * ra.y
                + W4c[s*8+2] * ra.z  + W4c[s*8+3] * ra.w;
            a2 += W4c[s*8+4] * rb_.x + W4c[s*8+5] * rb_.y
                + W4c[s*8+6] * rb_.z + W4c[s*8+7] * rb_.w;
            AdbS[(s * 32 + i) * 40 + v] = f2b(a2);
        }
    }
    __syncthreads();

    // MFMA: wave wv -> m-tiles {2wv,2wv+1}, n-tiles {0,1}, 9 taps
    int lane = tid & 63, wv = tid >> 6;
    int ml = lane & 15, qd = lane >> 4;
    f32x4 acc00 = {0.f, 0.f, 0.f, 0.f};
    f32x4 acc01 = acc00, acc10 = acc00, acc11 = acc00;
    int rowA0 = (wv * 2) * 16 + ml;
    #pragma unroll
    for (int s = 0; s < TS_; s++) {
        short8 a0 = *(const short8*)&xpadB[(rowA0 + s) * 40 + qd * 8];
        short8 a1 = *(const short8*)&xpadB[(rowA0 + 16 + s) * 40 + qd * 8];
        short8 b0 = *(const short8*)&AdbS[(s * 32 + ml) * 40 + qd * 8];
        short8 b1 = *(const short8*)&AdbS[(s * 32 + 16 + ml) * 40 + qd * 8];
        acc00 = __builtin_amdgcn_mfma_f32_16x16x32_bf16(a0, b0, acc00, 0, 0, 0);
        acc01 = __builtin_amdgcn_mfma_f32_16x16x32_bf16(a0, b1, acc01, 0, 0, 0);
        acc10 = __builtin_amdgcn_mfma_f32_16x16x32_bf16(a1, b0, acc10, 0, 0, 0);
        acc11 = __builtin_amdgcn_mfma_f32_16x16x32_bf16(a1, b1, acc11, 0, 0, 0);
    }

    bf16* zb = zws + (size_t)bc * TT_ * VV;
    int t0 = (wv * 2) * 16 + qd * 4;
    int i0 = ml, i1 = 16 + ml;
    #pragma unroll
    for (int r = 0; r < 4; r++) {
        zb[(t0 + r) * VV + i0]      = __float2bfloat16(acc00[r]);
        zb[(t0 + 16 + r) * VV + i0] = __float2bfloat16(acc10[r]);
    }
    if (i1 < VV) {
        #pragma unroll
        for (int r = 0; r < 4; r++) {
            zb[(t0 + r) * VV + i1]      = __float2bfloat16(acc01[r]);
            zb[(t0 + 16 + r) * VV + i1] = __float2bfloat16(acc11[r]);
        }
    }
}

// ---------------------------------------------------------------------------
// Kernel 4 (MFMA): out[b,o,tj] = sum_c W3[o,c]*z[b,c,tj] + b3[o]  -> fp32
// ---------------------------------------------------------------------------
__global__ __launch_bounds__(256) void k_conv3(const bf16* __restrict__ zws,
                                               const float* __restrict__ W3,
                                               const float* __restrict__ b3,
                                               float* __restrict__ out) {
    __shared__ __align__(16) unsigned short w3b[OO * 72];   // 9216 B
    __shared__ __align__(16) unsigned short zl[CC * 130];   // 16640 B
    __shared__ float b3l[OO];
    int tid = threadIdx.x;
    int b = blockIdx.x / 25, tile = blockIdx.x % 25;
    int tj0 = tile * 128;

    if (tid < OO) b3l[tid] = b3[tid];
    // W3 [o][c] fp32 -> bf16 LDS (A operand, k-contiguous), 4-wide packed
    const float4* W3v = (const float4*)W3;
    for (int idx = tid; idx < OO * CC / 4; idx += 256) {
        float4 f = W3v[idx];
        int o = idx >> 4, c4 = (idx & 15) * 4;
        s16x4 s4;
        s4[0] = (short)f2b(f.x);
        s4[1] = (short)f2b(f.y);
        s4[2] = (short)f2b(f.z);
        s4[3] = (short)f2b(f.w);
        *(s16x4*)&w3b[o * 72 + c4] = s4;
    }
    // z tile: natural [c][j] layout, packed uint copies (coalesced, conflict-free)
    const unsigned int* zg = (const unsigned int*)(zws + (size_t)b * CC * (TT_ * VV));
    for (int idu = tid; idu < CC * 64; idu += 256) {
        int c = idu >> 6, ju = idu & 63;
        ((unsigned int*)zl)[c * 65 + ju] = zg[c * 1600 + (tj0 >> 1) + ju];
    }
    __syncthreads();

    int lane = tid & 63, wv = tid >> 6;
    int ml = lane & 15, qd = lane >> 4;
    f32x4 acc[4][2];
    #pragma unroll
    for (int m = 0; m < 4; m++)
        #pragma unroll
        for (int nl = 0; nl < 2; nl++) acc[m][nl] = (f32x4){0.f, 0.f, 0.f, 0.f};

    #pragma unroll
    for (int k0 = 0; k0 < 2; k0++) {
        short8 a[4];
        #pragma unroll
        for (int m = 0; m < 4; m++)
            a[m] = *(const short8*)&w3b[(m * 16 + ml) * 72 + k0 * 32 + qd * 8];
        #pragma unroll
        for (int nl = 0; nl < 2; nl++) {
            int col = (2 * wv + nl) * 16 + ml;
            int cb = k0 * 32 + qd * 8;
            short8 bf;
            #pragma unroll
            for (int j = 0; j < 8; j++)
                bf[j] = (short)zl[(cb + j) * 130 + col];
            #pragma unroll
            for (int m = 0; m < 4; m++)
                acc[m][nl] = __builtin_amdgcn_mfma_f32_16x16x32_bf16(a[m], bf, acc[m][nl], 0, 0, 0);
        }
    }

    float* ob = out + (size_t)b * OO * (TT_ * VV) + tj0;
    #pragma unroll
    for (int m = 0; m < 4; m++)
        #pragma unroll
        for (int nl = 0; nl < 2; nl++) {
            int col = (2 * wv + nl) * 16 + ml;
            #pragma unroll
            for (int r = 0; r < 4; r++) {
                int o = m * 16 + qd * 4 + r;
                ob[(size_t)o * (TT_ * VV) + col] = acc[m][nl][r] + b3l[o];
            }
        }
}

// ---------------------------------------------------------------------------
extern "C" void kernel_launch(void* const* d_in, const int* in_sizes, int n_in,
                              void* d_out, int out_size, void* d_ws, size_t ws_size,
                              hipStream_t stream) {
    const float* x  = (const float*)d_in[0];
    const float* A  = (const float*)d_in[1];
    const float* W1 = (const float*)d_in[2];
    const float* b1 = (const float*)d_in[3];
    const float* W2 = (const float*)d_in[4];
    const float* b2 = (const float*)d_in[5];
    const float* W4 = (const float*)d_in[6];
    const float* b4 = (const float*)d_in[7];
    const float* W3 = (const float*)d_in[8];
    const float* b3 = (const float*)d_in[9];
    float* out = (float*)d_out;

    char* ws = (char*)d_ws;
    float* xm   = (float*)(ws);                         // 102400 * 4
    float* rel  = (float*)(ws + 409600);                // 320000 * 4
    bf16*  zws  = (bf16*)(ws + 1689600);                // 13107200 * 2

    k_mean <<<BB * CC, 256, 0, stream>>>(x, xm);
    k_rel  <<<BB * 5,  256, 0, stream>>>(xm, W1, b1, W2, b2, rel);
    k_z    <<<BB * CC, 256, 0, stream>>>(x, A, W4, b4, rel, zws);
    k_conv3<<<BB * 25, 256, 0, stream>>>(zws, W3, b3, out);
}